// Round 3
// baseline (143.255 us; speedup 1.0000x reference)
//
#include <hip/hip_runtime.h>
#include <math.h>

// ModulationIndex as MFMA GEMM, v3: T-split for 2 blocks/CU.
// amp_sums[p*18+k, a] = sum_t onehot[pk, t] * amp[a, t]
// Grid 512: block = (group g, t-half). Each block: 192x32x1024 f16 GEMM.
// 8 waves = 4 m-quarters x 2 k-halves (48 acc VGPRs). Bins as u16 in LDS;
// onehot A-fragments via packed 16-bit compare. B = amp split hi + lo*4096
// (f16 pair) staged per 256-t tile. Partial sums -> ws; mi_ent fuses
// cross-half combine + entropy + s-mean.

#define FP_ 10
#define FA_ 30
#define K_  18
#define T_  2048
#define TH_ 1024   // t per block
#define TC_ 256    // t per LDS tile
#define NTILE 4
#define RS_ 132    // amp row stride (u32): 128 data + 4 pad
#define BS_ 516    // binsw row stride (u32): 512 data + 4 pad
#define NT_ 512

typedef _Float16 half8 __attribute__((ext_vector_type(8)));
typedef float    f32x4 __attribute__((ext_vector_type(4)));
typedef unsigned short u16x2 __attribute__((ext_vector_type(2)));
typedef short          s16x2 __attribute__((ext_vector_type(2)));

// LDS: [0,128) cutoffs | [128,20768) binsw 10x516 u32 | [20768,37664) amp_h
//      [37664,54560) amp_l | red (4 x 48x33 f32 = 25344 B) aliased at 128.
#define LDS_BYTES 54560

static __device__ __forceinline__ unsigned onehot2(unsigned w, unsigned kk) {
  const u16x2 x  = __builtin_bit_cast(u16x2, w ^ kk);
  const s16x2 eq = (s16x2)(x == (u16x2)(unsigned short)0);   // -1 where halves equal
  const u16x2 m  = __builtin_bit_cast(u16x2, eq) & (u16x2)(unsigned short)0x3C00;
  return __builtin_bit_cast(unsigned, m);
}

__global__ __launch_bounds__(NT_, 4)
void mi_main(const float* __restrict__ pha, const float* __restrict__ amp,
             float* __restrict__ ws) {
  extern __shared__ unsigned char smem[];
  float*    c_lds = (float*)smem;
  unsigned* binsw = (unsigned*)(smem + 128);
  unsigned* amp_h = (unsigned*)(smem + 20768);
  unsigned* amp_l = (unsigned*)(smem + 37664);
  float*    red   = (float*)(smem + 128);     // aliased; used after last barrier

  const int tid  = threadIdx.x;
  const int lane = tid & 63;
  const int wv   = tid >> 6;
  const int quad = lane >> 4;
  const int lc   = lane & 15;
  const int mq   = wv & 3;    // m-quarter: rows mq*48..+47
  const int q2   = wv >> 2;   // k-half

  const int bid  = blockIdx.x;
  const int g    = bid >> 1;
  const int half = bid & 1;
  const int s    = g & 3;
  const int bc   = g >> 2;
  const long pha_base = (long)bc * (FP_ * 4L * T_) + (long)s * T_ + half * TH_;
  const long amp_base = (long)bc * (FA_ * 4L * T_) + (long)s * T_ + half * TH_;

  // cutoffs: bit-exact np.linspace(-pi, pi, 19) (f64 math, f32 cast)
  if (tid < 19) {
    const double PI_D = 3.14159265358979323846264338327950288;
    const double step = (2.0 * PI_D) / 18.0;
    c_lds[tid] = (tid == 18) ? (float)PI_D : (float)(-PI_D + (double)tid * step);
  }
  // static B rows: 30 = ones (counts), 31 = zero pad
  for (int i = tid; i < RS_; i += NT_) {
    amp_h[30 * RS_ + i] = 0x3C003C00u;
    amp_h[31 * RS_ + i] = 0u;
    amp_l[30 * RS_ + i] = 0u;
    amp_l[31 * RS_ + i] = 0u;
  }
  __syncthreads();

  // per-wave row tables: 3 m-tiles of 16 rows each
  int p_mt[3]; unsigned kk_mt[3];
  #pragma unroll
  for (int mt = 0; mt < 3; ++mt) {
    const int row = mq * 48 + mt * 16 + lc;
    int p = row / 18; p = min(p, 9);
    const unsigned kb = (unsigned)(row - p * 18);  // >=18 on pad rows: never matches
    p_mt[mt] = p;
    kk_mt[mt] = kb | (kb << 16);
  }

  // --- bins: each thread 2 consecutive t per p; u16 bins, 2 per u32.
  const float PI_F    = 3.14159274101257324f;
  const float INVSTEP = 2.8647890f;
  #pragma unroll
  for (int p = 0; p < FP_; ++p) {
    const float2 v = *(const float2*)(pha + pha_base + (long)p * (4L * T_) + tid * 2);
    float xs[2] = {v.x, v.y};
    unsigned pk = 0;
    #pragma unroll
    for (int j = 0; j < 2; ++j) {
      const float x = xs[j];
      int gi = (int)((x + PI_F) * INVSTEP);
      gi = min(17, max(0, gi));
      if (x <= c_lds[gi]) gi -= 1;        // searchsorted-left: c_b < x <= c_{b+1}
      else if (x > c_lds[gi + 1]) gi += 1;
      gi = min(17, max(0, gi));
      pk |= ((unsigned)gi) << (16 * j);
    }
    binsw[p * BS_ + tid] = pk;
  }

  // --- amp staging: 480 threads, row = tid>>4, 16-t segment = tid&15.
  const bool stager = tid < 480;
  const int a_row = tid >> 4;
  const int seg   = tid & 15;
  const float* gsrc = amp + amp_base + (long)a_row * (4L * T_) + seg * 16;
  float4 vreg[4];
  if (stager) {
    #pragma unroll
    for (int j = 0; j < 4; ++j) vreg[j] = *(const float4*)(gsrc + j * 4);
  }

  f32x4 acch[3][2], accl[3][2];
  #pragma unroll
  for (int mt = 0; mt < 3; ++mt) {
    acch[mt][0] = (f32x4){0.f,0.f,0.f,0.f}; acch[mt][1] = (f32x4){0.f,0.f,0.f,0.f};
    accl[mt][0] = (f32x4){0.f,0.f,0.f,0.f}; accl[mt][1] = (f32x4){0.f,0.f,0.f,0.f};
  }
  __syncthreads();   // bins + cutoffs visible

  for (int tile = 0; tile < NTILE; ++tile) {
    if (stager) {   // convert + write staged tile (hi f16, lo f16*4096)
      unsigned hw[8], lw[8];
      #pragma unroll
      for (int j = 0; j < 4; ++j) {
        const float xv[4] = {vreg[j].x, vreg[j].y, vreg[j].z, vreg[j].w};
        #pragma unroll
        for (int e = 0; e < 4; e += 2) {
          _Float16 h0 = (_Float16)xv[e];
          _Float16 h1 = (_Float16)xv[e + 1];
          _Float16 l0 = (_Float16)((xv[e]     - (float)h0) * 4096.0f);
          _Float16 l1 = (_Float16)((xv[e + 1] - (float)h1) * 4096.0f);
          hw[j*2 + e/2] = (unsigned)__builtin_bit_cast(unsigned short, h0)
                        | ((unsigned)__builtin_bit_cast(unsigned short, h1) << 16);
          lw[j*2 + e/2] = (unsigned)__builtin_bit_cast(unsigned short, l0)
                        | ((unsigned)__builtin_bit_cast(unsigned short, l1) << 16);
        }
      }
      unsigned* dh = &amp_h[a_row * RS_ + seg * 8];
      unsigned* dl = &amp_l[a_row * RS_ + seg * 8];
      ((uint4*)dh)[0] = make_uint4(hw[0], hw[1], hw[2], hw[3]);
      ((uint4*)dh)[1] = make_uint4(hw[4], hw[5], hw[6], hw[7]);
      ((uint4*)dl)[0] = make_uint4(lw[0], lw[1], lw[2], lw[3]);
      ((uint4*)dl)[1] = make_uint4(lw[4], lw[5], lw[6], lw[7]);
    }
    __syncthreads();
    if (stager && tile < NTILE - 1) {   // prefetch next tile during compute
      #pragma unroll
      for (int j = 0; j < 4; ++j)
        vreg[j] = *(const float4*)(gsrc + (tile + 1) * TC_ + j * 4);
    }

    #pragma unroll
    for (int ci = 0; ci < 4; ++ci) {
      const int cl   = q2 * 4 + ci;          // 32-t chunk 0..7
      const int boff = cl * 16 + quad * 4;   // u32 offset in amp row
      const half8 bh0 = __builtin_bit_cast(half8, *(const uint4*)&amp_h[lc * RS_ + boff]);
      const half8 bh1 = __builtin_bit_cast(half8, *(const uint4*)&amp_h[(16 + lc) * RS_ + boff]);
      const half8 bl0 = __builtin_bit_cast(half8, *(const uint4*)&amp_l[lc * RS_ + boff]);
      const half8 bl1 = __builtin_bit_cast(half8, *(const uint4*)&amp_l[(16 + lc) * RS_ + boff]);
      const int widx = tile * 128 + cl * 16 + quad * 4;   // u32 idx in binsw row
      #pragma unroll
      for (int mt = 0; mt < 3; ++mt) {
        const uint4 wb = *(const uint4*)&binsw[p_mt[mt] * BS_ + widx];
        const unsigned kk = kk_mt[mt];
        const half8 af = __builtin_bit_cast(half8,
            make_uint4(onehot2(wb.x, kk), onehot2(wb.y, kk),
                       onehot2(wb.z, kk), onehot2(wb.w, kk)));
        acch[mt][0] = __builtin_amdgcn_mfma_f32_16x16x32_f16(af, bh0, acch[mt][0], 0, 0, 0);
        accl[mt][0] = __builtin_amdgcn_mfma_f32_16x16x32_f16(af, bl0, accl[mt][0], 0, 0, 0);
        acch[mt][1] = __builtin_amdgcn_mfma_f32_16x16x32_f16(af, bh1, acch[mt][1], 0, 0, 0);
        accl[mt][1] = __builtin_amdgcn_mfma_f32_16x16x32_f16(af, bl1, accl[mt][1], 0, 0, 0);
      }
    }
    __syncthreads();
  }

  // combine hi + lo/4096
  f32x4 acc[3][2];
  #pragma unroll
  for (int mt = 0; mt < 3; ++mt) {
    acc[mt][0] = acch[mt][0] + accl[mt][0] * 2.44140625e-4f;
    acc[mt][1] = acch[mt][1] + accl[mt][1] * 2.44140625e-4f;
  }

  // --- combine the 2 k-halves via LDS (red aliases binsw/amp: safe after barrier)
  // C/D layout: col = lane&15, row = quad*4 + reg.
  if (q2 == 1) {
    float* S = &red[mq * 48 * 33];
    #pragma unroll
    for (int mt = 0; mt < 3; ++mt)
      #pragma unroll
      for (int n = 0; n < 2; ++n)
        #pragma unroll
        for (int r = 0; r < 4; ++r)
          S[(mt * 16 + quad * 4 + r) * 33 + n * 16 + lc] = acc[mt][n][r];
  }
  __syncthreads();
  if (q2 == 0) {
    float* S = &red[mq * 48 * 33];
    float* W = ws + (long)bid * 6144;
    #pragma unroll
    for (int mt = 0; mt < 3; ++mt)
      #pragma unroll
      for (int n = 0; n < 2; ++n)
        #pragma unroll
        for (int r = 0; r < 4; ++r) {
          const float v = acc[mt][n][r] + S[(mt * 16 + quad * 4 + r) * 33 + n * 16 + lc];
          W[(mq * 48 + mt * 16 + quad * 4 + r) * 32 + n * 16 + lc] = v;
        }
  }
}

// Fused: combine t-halves, entropy, mean over s. One block per bc.
__global__ __launch_bounds__(320)
void mi_ent(const float* __restrict__ ws, float* __restrict__ out) {
  const int bc = blockIdx.x;
  const int t  = threadIdx.x;
  if (t >= FP_ * FA_) return;
  const int p = t / FA_;
  const int a = t - p * FA_;
  const float L = logf(18.0f);
  float mi_sum = 0.0f;
  for (int s = 0; s < 4; ++s) {
    const float* w0 = ws + ((long)(bc * 4 + s) * 2) * 6144;
    const float* w1 = w0 + 6144;
    float m[K_];
    float tot = 0.0f;
    #pragma unroll
    for (int k = 0; k < K_; ++k) {
      const int r = (p * K_ + k) * 32;
      const float cnt = w0[r + 30] + w1[r + 30];
      const float sv  = w0[r + a]  + w1[r + a];
      const float mk  = sv / (cnt + 1e-9f);
      m[k] = mk;
      tot += mk;
    }
    const float denom = tot + 1e-9f;
    float ent = 0.0f;
    #pragma unroll
    for (int k = 0; k < K_; ++k) {
      const float pr = m[k] / denom;
      ent += pr * logf(pr + 1e-9f);
    }
    mi_sum += (L + ent) / L;
  }
  out[bc * (FP_ * FA_) + t] = mi_sum * 0.25f;
}

extern "C" void kernel_launch(void* const* d_in, const int* in_sizes, int n_in,
                              void* d_out, int out_size, void* d_ws, size_t ws_size,
                              hipStream_t stream) {
  const float* pha = (const float*)d_in[0];
  const float* amp = (const float*)d_in[1];
  float* out = (float*)d_out;
  float* ws  = (float*)d_ws;   // 512 * 6144 f32 = 12.6 MB partial sums

  static bool attr_set = false;
  if (!attr_set) {
    hipFuncSetAttribute((const void*)mi_main,
                        hipFuncAttributeMaxDynamicSharedMemorySize, LDS_BYTES);
    attr_set = true;
  }
  hipLaunchKernelGGL(mi_main, dim3(512), dim3(NT_), LDS_BYTES, stream, pha, amp, ws);
  hipLaunchKernelGGL(mi_ent, dim3(64), dim3(320), 0, stream, ws, out);
}

// Round 4
// 141.495 us; speedup vs baseline: 1.0124x; 1.0124x over previous
//
#include <hip/hip_runtime.h>
#include <math.h>

// ModulationIndex as MFMA GEMM, v4: ping-pong LDS (1 barrier/tile), u8 bins,
// perm-based onehot A-gen, parallel entropy epilogue.
// amp_sums[p*18+k, a] = sum_t onehot[pk, t] * amp[a, t]
// Grid 512 = (group, t-half); 512 thr; 2 blocks/CU (78KB LDS each).
// 8 waves = 4 m-quarters x 2 k-halves. B = amp hi/lo f16 (lo*4096).

#define FP_ 10
#define FA_ 30
#define K_  18
#define T_  2048
#define TH_ 1024
#define TC_ 256
#define RS_ 132    // u32 per amp row: 128 data + 4 pad (16B-aligned rows)
#define BS8_ 258   // u32 per bins row: 256 data + 2 pad (even -> b64 aligned)
#define NT_ 512

#define OFF_BINS 128
#define OFF_AMP  10448            // 128 + 10*258*4 = 10448
#define AMPSZ    16896            // 32*132*4
#define LDS_BYTES (OFF_AMP + 4 * AMPSZ)   // 78032; x2 blocks = 156064 <= 160K

typedef _Float16 half8 __attribute__((ext_vector_type(8)));
typedef float    f32x4 __attribute__((ext_vector_type(4)));

// onehot for 4 u8 bins packed in w vs kb4 (kb replicated): two u32 f16-pair
// masks (0x3C00 where bin==kb).  zero-byte trick + v_perm spread + *0x78.
static __device__ __forceinline__ uint2 oh4(unsigned w, unsigned kb4) {
  const unsigned x = w ^ kb4;
  const unsigned t = (x & 0x7F7F7F7Fu) + 0x7F7F7F7Fu;
  const unsigned m = ~(t | x) & 0x80808080u;            // 0x80 at matching bytes
  const unsigned p0 = __builtin_amdgcn_perm(0u, m, 0x04010400u) * 0x78u;
  const unsigned p1 = __builtin_amdgcn_perm(0u, m, 0x04030402u) * 0x78u;
  return make_uint2(p0, p1);
}

__global__ __launch_bounds__(NT_, 4)
void mi_main(const float* __restrict__ pha, const float* __restrict__ amp,
             float* __restrict__ ws) {
  extern __shared__ unsigned char smem[];
  float*    c_lds = (float*)smem;
  unsigned* binsw = (unsigned*)(smem + OFF_BINS);
  float*    red   = (float*)(smem + OFF_AMP);   // aliases amp buf0 after K-loop

  const int tid  = threadIdx.x;
  const int lane = tid & 63;
  const int wv   = tid >> 6;
  const int quad = lane >> 4;
  const int lc   = lane & 15;
  const int mq   = wv & 3;    // m-quarter: rows mq*48..+47
  const int q2   = wv >> 2;   // k-half

  const int bid  = blockIdx.x;
  const int g    = bid >> 1;
  const int half = bid & 1;
  const int s    = g & 3;
  const int bc   = g >> 2;
  const long pha_base = (long)bc * (FP_ * 4L * T_) + (long)s * T_ + half * TH_;
  const long amp_base = (long)bc * (FA_ * 4L * T_) + (long)s * T_ + half * TH_;

  // cutoffs: bit-exact np.linspace(-pi, pi, 19) (f64 math, f32 cast)
  if (tid < 19) {
    const double PI_D = 3.14159265358979323846264338327950288;
    const double step = (2.0 * PI_D) / 18.0;
    c_lds[tid] = (tid == 18) ? (float)PI_D : (float)(-PI_D + (double)tid * step);
  }
  // static B rows 30 (ones -> counts) / 31 (pad) in BOTH buffers
  for (int i = tid; i < 4 * RS_; i += NT_) {
    const int b2 = i / RS_, c = i - b2 * RS_;             // b2 = buf*2+hl
    unsigned* A = (unsigned*)(smem + OFF_AMP + b2 * AMPSZ);
    A[30 * RS_ + c] = (b2 & 1) ? 0u : 0x3C003C00u;
    A[31 * RS_ + c] = 0u;
  }
  __syncthreads();

  // prefetch amp tile 0 (latency hidden under bins phase)
  const bool stager = tid < 480;
  const int a_row = tid >> 4;
  const int seg   = tid & 15;
  const float* gsrc = amp + amp_base + (long)a_row * (4L * T_) + seg * 16;
  float4 vreg[4];
  if (stager) {
    #pragma unroll
    for (int j = 0; j < 4; ++j) vreg[j] = *(const float4*)(gsrc + j * 4);
  }

  // --- bins: 2560 u32 words, 4 t each (u8 bins).
  const float PI_F    = 3.14159274101257324f;
  const float INVSTEP = 2.8647890f;
  #pragma unroll
  for (int it = 0; it < 5; ++it) {
    const int i = it * NT_ + tid;
    const int p = i >> 8, w = i & 255;
    const float4 v = *(const float4*)(pha + pha_base + (long)p * (4L * T_) + w * 4);
    const float xs[4] = {v.x, v.y, v.z, v.w};
    unsigned pk = 0;
    #pragma unroll
    for (int j = 0; j < 4; ++j) {
      const float x = xs[j];
      int gi = (int)((x + PI_F) * INVSTEP);
      gi = min(17, max(0, gi));
      if (x <= c_lds[gi]) gi -= 1;        // searchsorted-left: c_b < x <= c_{b+1}
      else if (x > c_lds[gi + 1]) gi += 1;
      gi = min(17, max(0, gi));
      pk |= ((unsigned)gi) << (8 * j);
    }
    binsw[p * BS8_ + w] = pk;
  }

  // per-wave row tables
  int p_mt[3]; unsigned kb4_mt[3];
  #pragma unroll
  for (int mt = 0; mt < 3; ++mt) {
    const int row = mq * 48 + mt * 16 + lc;
    int p = row / 18; p = min(p, 9);
    const unsigned kb = (unsigned)(row - p * 18);   // >=18 on pad rows
    p_mt[mt] = p;
    kb4_mt[mt] = kb * 0x01010101u;
  }

  f32x4 acch[3][2], accl[3][2];
  #pragma unroll
  for (int mt = 0; mt < 3; ++mt) {
    acch[mt][0] = (f32x4){0.f,0.f,0.f,0.f}; acch[mt][1] = (f32x4){0.f,0.f,0.f,0.f};
    accl[mt][0] = (f32x4){0.f,0.f,0.f,0.f}; accl[mt][1] = (f32x4){0.f,0.f,0.f,0.f};
  }

  // convert tile0 -> buf0, then prefetch tile1
  #define CONVERT_WRITE(NXT) do {                                              \
    unsigned hw[8], lw[8];                                                     \
    _Pragma("unroll")                                                          \
    for (int j = 0; j < 4; ++j) {                                              \
      const float xv[4] = {vreg[j].x, vreg[j].y, vreg[j].z, vreg[j].w};        \
      _Pragma("unroll")                                                        \
      for (int e = 0; e < 4; e += 2) {                                         \
        _Float16 h0 = (_Float16)xv[e];                                         \
        _Float16 h1 = (_Float16)xv[e + 1];                                     \
        _Float16 l0 = (_Float16)((xv[e]     - (float)h0) * 4096.0f);           \
        _Float16 l1 = (_Float16)((xv[e + 1] - (float)h1) * 4096.0f);           \
        hw[j*2 + e/2] = (unsigned)__builtin_bit_cast(unsigned short, h0)       \
                      | ((unsigned)__builtin_bit_cast(unsigned short, h1)<<16);\
        lw[j*2 + e/2] = (unsigned)__builtin_bit_cast(unsigned short, l0)       \
                      | ((unsigned)__builtin_bit_cast(unsigned short, l1)<<16);\
      }                                                                        \
    }                                                                          \
    unsigned* dh = (unsigned*)(smem + OFF_AMP + ((NXT)*2+0)*AMPSZ) + a_row*RS_ + seg*8; \
    unsigned* dl = (unsigned*)(smem + OFF_AMP + ((NXT)*2+1)*AMPSZ) + a_row*RS_ + seg*8; \
    ((uint4*)dh)[0] = make_uint4(hw[0], hw[1], hw[2], hw[3]);                  \
    ((uint4*)dh)[1] = make_uint4(hw[4], hw[5], hw[6], hw[7]);                  \
    ((uint4*)dl)[0] = make_uint4(lw[0], lw[1], lw[2], lw[3]);                  \
    ((uint4*)dl)[1] = make_uint4(lw[4], lw[5], lw[6], lw[7]);                  \
  } while (0)

  if (stager) {
    CONVERT_WRITE(0);
    #pragma unroll
    for (int j = 0; j < 4; ++j) vreg[j] = *(const float4*)(gsrc + TC_ + j * 4);
  }
  __syncthreads();   // binsw + buf0 visible

  #pragma unroll
  for (int tile = 0; tile < 4; ++tile) {
    const int cur = tile & 1;
    const unsigned* Ah = (const unsigned*)(smem + OFF_AMP + (cur*2+0)*AMPSZ);
    const unsigned* Al = (const unsigned*)(smem + OFF_AMP + (cur*2+1)*AMPSZ);
    #pragma unroll
    for (int ci = 0; ci < 4; ++ci) {
      const int cl   = q2 * 4 + ci;
      const int boff = cl * 16 + quad * 4;
      const half8 bh0 = __builtin_bit_cast(half8, *(const uint4*)&Ah[lc * RS_ + boff]);
      const half8 bh1 = __builtin_bit_cast(half8, *(const uint4*)&Ah[(16 + lc) * RS_ + boff]);
      const half8 bl0 = __builtin_bit_cast(half8, *(const uint4*)&Al[lc * RS_ + boff]);
      const half8 bl1 = __builtin_bit_cast(half8, *(const uint4*)&Al[(16 + lc) * RS_ + boff]);
      const int widx = tile * 64 + cl * 8 + quad * 2;
      #pragma unroll
      for (int mt = 0; mt < 3; ++mt) {
        const uint2 wb = *(const uint2*)&binsw[p_mt[mt] * BS8_ + widx];
        const uint2 m0 = oh4(wb.x, kb4_mt[mt]);
        const uint2 m1 = oh4(wb.y, kb4_mt[mt]);
        const half8 af = __builtin_bit_cast(half8, make_uint4(m0.x, m0.y, m1.x, m1.y));
        acch[mt][0] = __builtin_amdgcn_mfma_f32_16x16x32_f16(af, bh0, acch[mt][0], 0, 0, 0);
        accl[mt][0] = __builtin_amdgcn_mfma_f32_16x16x32_f16(af, bl0, accl[mt][0], 0, 0, 0);
        acch[mt][1] = __builtin_amdgcn_mfma_f32_16x16x32_f16(af, bh1, acch[mt][1], 0, 0, 0);
        accl[mt][1] = __builtin_amdgcn_mfma_f32_16x16x32_f16(af, bl1, accl[mt][1], 0, 0, 0);
      }
    }
    // stage tile+1 into the other buffer within the SAME barrier phase
    if (tile < 3 && stager) {
      const int nxt = cur ^ 1;
      CONVERT_WRITE(nxt);
      if (tile < 2) {
        #pragma unroll
        for (int j = 0; j < 4; ++j)
          vreg[j] = *(const float4*)(gsrc + (tile + 2) * TC_ + j * 4);
      }
    }
    if (tile < 3) __syncthreads();
  }

  // combine hi + lo/4096
  f32x4 acc[3][2];
  #pragma unroll
  for (int mt = 0; mt < 3; ++mt) {
    acc[mt][0] = acch[mt][0] + accl[mt][0] * 2.44140625e-4f;
    acc[mt][1] = acch[mt][1] + accl[mt][1] * 2.44140625e-4f;
  }

  // k-half combine via red (aliases buf0 region: last tile read buf1 only).
  // C/D layout: col = lane&15, row = quad*4 + reg.
  if (q2 == 1) {
    float* S = &red[mq * 48 * 33];
    #pragma unroll
    for (int mt = 0; mt < 3; ++mt)
      #pragma unroll
      for (int n = 0; n < 2; ++n)
        #pragma unroll
        for (int r = 0; r < 4; ++r)
          S[(mt * 16 + quad * 4 + r) * 33 + n * 16 + lc] = acc[mt][n][r];
  }
  __syncthreads();
  if (q2 == 0) {
    float* S = &red[mq * 48 * 33];
    float* W = ws + (long)bid * 6144;
    #pragma unroll
    for (int mt = 0; mt < 3; ++mt)
      #pragma unroll
      for (int n = 0; n < 2; ++n)
        #pragma unroll
        for (int r = 0; r < 4; ++r) {
          const float v = acc[mt][n][r] + S[(mt * 16 + quad * 4 + r) * 33 + n * 16 + lc];
          W[(mq * 48 + mt * 16 + quad * 4 + r) * 32 + n * 16 + lc] = v;
        }
  }
}

// Epilogue: one block per (bc, p). Stage 8x18x32 table coalesced into LDS,
// 120 threads (s,a) compute entropy, 30 threads reduce s.
__global__ __launch_bounds__(256)
void mi_ent(const float* __restrict__ ws, float* __restrict__ out) {
  __shared__ float tbl[8 * 576];   // [sub][k*32+c]
  __shared__ float red[4][32];
  const int bc = blockIdx.x / FP_;
  const int p  = blockIdx.x - bc * FP_;
  const int tid = threadIdx.x;

  #pragma unroll
  for (int it = 0; it < 18; ++it) {
    const int i = it * 256 + tid;
    const int sub = i / 576, r = i - sub * 576;
    tbl[i] = ws[(long)(bc * 8 + sub) * 6144 + p * 576 + r];
  }
  __syncthreads();

  if (tid < 120) {
    const int s = tid / FA_;
    const int a = tid - s * FA_;
    const float* t0 = &tbl[(2 * s) * 576];
    const float* t1 = &tbl[(2 * s + 1) * 576];
    float m[K_];
    float tot = 0.0f;
    #pragma unroll
    for (int k = 0; k < K_; ++k) {
      const float cnt = t0[k * 32 + 30] + t1[k * 32 + 30];
      const float sv  = t0[k * 32 + a]  + t1[k * 32 + a];
      const float mk  = sv / (cnt + 1e-9f);
      m[k] = mk;
      tot += mk;
    }
    const float denom = tot + 1e-9f;
    float ent = 0.0f;
    #pragma unroll
    for (int k = 0; k < K_; ++k) {
      const float pr = m[k] / denom;
      ent += pr * logf(pr + 1e-9f);
    }
    const float L = logf(18.0f);
    red[s][a] = (L + ent) / L;
  }
  __syncthreads();
  if (tid < FA_)
    out[(bc * FP_ + p) * FA_ + tid] =
        0.25f * (red[0][tid] + red[1][tid] + red[2][tid] + red[3][tid]);
}

extern "C" void kernel_launch(void* const* d_in, const int* in_sizes, int n_in,
                              void* d_out, int out_size, void* d_ws, size_t ws_size,
                              hipStream_t stream) {
  const float* pha = (const float*)d_in[0];
  const float* amp = (const float*)d_in[1];
  float* out = (float*)d_out;
  float* ws  = (float*)d_ws;   // 512 * 6144 f32 = 12.6 MB partials

  static bool attr_set = false;
  if (!attr_set) {
    hipFuncSetAttribute((const void*)mi_main,
                        hipFuncAttributeMaxDynamicSharedMemorySize, LDS_BYTES);
    attr_set = true;
  }
  hipLaunchKernelGGL(mi_main, dim3(512), dim3(NT_), LDS_BYTES, stream, pha, amp, ws);
  hipLaunchKernelGGL(mi_ent, dim3(64 * FP_), dim3(256), 0, stream, ws, out);
}